// Round 1
// baseline (1200.204 us; speedup 1.0000x reference)
//
#include <hip/hip_runtime.h>
#include <hip/hip_bf16.h>
#include <cstdint>
#include <cstddef>

// Problem constants (match reference setup_inputs)
#define NN 100000     // nodes
#define NE 1600000    // edges
#define NG 64         // graphs
// IN=64, H=128, EMB=64

// ---------------- helpers ----------------

__device__ __forceinline__ int lower_bound_i(const int* __restrict__ a, int n, int v) {
  int lo = 0, hi = n;
  while (lo < hi) { int m = (lo + hi) >> 1; if (a[m] < v) lo = m + 1; else hi = m; }
  return lo;
}

// ---------------- CSR build ----------------

__global__ void zero_kernel(int* __restrict__ deg, float* __restrict__ pooled, int n, int np) {
  int i = blockIdx.x * blockDim.x + threadIdx.x;
  if (i < n) deg[i] = 0;
  if (i < np) pooled[i] = 0.f;
}

__global__ void count_deg_kernel(const int* __restrict__ dst, int* __restrict__ deg, int e) {
  int i = blockIdx.x * blockDim.x + threadIdx.x;
  if (i < e) atomicAdd(&deg[dst[i]], 1);
}

// single-block hierarchical exclusive scan (wave shfl scan + serial wave-sum scan)
__global__ __launch_bounds__(1024) void scan_kernel(const int* __restrict__ deg,
                                                    int* __restrict__ rs, int n) {
  __shared__ int wsum[16];
  __shared__ int carry;
  int tid = threadIdx.x, lane = tid & 63, wid = tid >> 6;
  if (tid == 0) carry = 0;
  __syncthreads();
  for (int base = 0; base < n; base += 1024) {
    int i = base + tid;
    int v = (i < n) ? deg[i] : 0;
    int incl = v;
    #pragma unroll
    for (int off = 1; off < 64; off <<= 1) {
      int t = __shfl_up(incl, off, 64);
      if (lane >= off) incl += t;
    }
    if (lane == 63) wsum[wid] = incl;
    __syncthreads();
    if (tid == 0) {
      int acc = carry;
      #pragma unroll
      for (int j = 0; j < 16; ++j) { int t = wsum[j]; wsum[j] = acc; acc += t; }
      carry = acc;
    }
    __syncthreads();
    int excl = incl - v + wsum[wid];
    if (i < n) rs[i] = excl;
    __syncthreads();  // protect wsum for next chunk
  }
  if (tid == 0) rs[n] = carry;
}

__global__ void init_cursor_kernel(const int* __restrict__ rs, int* __restrict__ cur, int n) {
  int i = blockIdx.x * blockDim.x + threadIdx.x;
  if (i < n) cur[i] = rs[i];
}

__global__ void fill_csr_kernel(const int* __restrict__ src, const int* __restrict__ dst,
                                int* __restrict__ cur, int* __restrict__ col, int e) {
  int i = blockIdx.x * blockDim.x + threadIdx.x;
  if (i < e) {
    int p = atomicAdd(&cur[dst[i]], 1);
    col[p] = src[i];
  }
}

// ---------------- mean aggregation (gather over CSR) ----------------
// one wave per destination node; lanes = feature dims

__global__ __launch_bounds__(256) void aggregate64_kernel(const float* __restrict__ X,
                                                          const int* __restrict__ rs,
                                                          const int* __restrict__ col,
                                                          float* __restrict__ out, int n) {
  int lane = threadIdx.x & 63;
  int node = blockIdx.x * 4 + (threadIdx.x >> 6);
  if (node >= n) return;
  int a = rs[node], b = rs[node + 1];
  float acc = 0.f;
  for (int jb = a; jb < b; jb += 64) {
    int v = 0;
    if (jb + lane < b) v = col[jb + lane];
    int cnt = min(64, b - jb);
    for (int t = 0; t < cnt; ++t) {
      int s = __shfl(v, t, 64);
      acc += X[(size_t)s * 64 + lane];
    }
  }
  int d = b - a;
  float inv = d > 0 ? 1.0f / (float)d : 0.f;   // clip(deg,1): deg=0 -> sum=0 -> 0
  out[(size_t)node * 64 + lane] = acc * inv;
}

__global__ __launch_bounds__(256) void aggregate128_kernel(const float* __restrict__ X,
                                                           const int* __restrict__ rs,
                                                           const int* __restrict__ col,
                                                           float* __restrict__ out, int n) {
  int lane = threadIdx.x & 63;
  int node = blockIdx.x * 4 + (threadIdx.x >> 6);
  if (node >= n) return;
  int a = rs[node], b = rs[node + 1];
  const float2* __restrict__ X2 = (const float2*)X;
  float ax = 0.f, ay = 0.f;
  for (int jb = a; jb < b; jb += 64) {
    int v = 0;
    if (jb + lane < b) v = col[jb + lane];
    int cnt = min(64, b - jb);
    for (int t = 0; t < cnt; ++t) {
      int s = __shfl(v, t, 64);
      float2 f = X2[(size_t)s * 64 + lane];
      ax += f.x; ay += f.y;
    }
  }
  int d = b - a;
  float inv = d > 0 ? 1.0f / (float)d : 0.f;
  float2 o; o.x = ax * inv; o.y = ay * inv;
  ((float2*)out)[(size_t)node * 64 + lane] = o;
}

// ---------------- fused SAGE GEMM: Out = relu(Mean@Wl + X@Wr + b) ----------------
// block = 1 wave = 64 threads, NT nodes per block. Row addresses are block-uniform
// -> activation loads become s_load (SGPR broadcast); weight loads are vector,
// reused NT times per block. H fixed at 128 (lane covers f and f+64).

template <int K, int NT>
__global__ __launch_bounds__(64) void sage_gemm_kernel(const float* __restrict__ Mean,
                                                       const float* __restrict__ X,
                                                       const float* __restrict__ Wl,
                                                       const float* __restrict__ Wr,
                                                       const float* __restrict__ bias,
                                                       float* __restrict__ Out) {
  int lane = threadIdx.x;
  long n0 = (long)blockIdx.x * NT;
  float acc0[NT], acc1[NT];
  #pragma unroll
  for (int i = 0; i < NT; ++i) { acc0[i] = 0.f; acc1[i] = 0.f; }
  const float* __restrict__ mrow = Mean + n0 * K;
  const float* __restrict__ xrow = X + n0 * K;
  #pragma unroll 4
  for (int k = 0; k < K; ++k) {
    float wl0 = Wl[k * 128 + lane];
    float wl1 = Wl[k * 128 + 64 + lane];
    float wr0 = Wr[k * 128 + lane];
    float wr1 = Wr[k * 128 + 64 + lane];
    #pragma unroll
    for (int i = 0; i < NT; ++i) {
      float m = mrow[(size_t)i * K + k];   // uniform -> s_load
      float xv = xrow[(size_t)i * K + k];  // uniform -> s_load
      acc0[i] = fmaf(m, wl0, acc0[i]);
      acc0[i] = fmaf(xv, wr0, acc0[i]);
      acc1[i] = fmaf(m, wl1, acc1[i]);
      acc1[i] = fmaf(xv, wr1, acc1[i]);
    }
  }
  float b0 = bias[lane], b1 = bias[64 + lane];
  #pragma unroll
  for (int i = 0; i < NT; ++i) {
    long n = n0 + i;
    Out[n * 128 + lane]      = fmaxf(acc0[i] + b0, 0.f);
    Out[n * 128 + 64 + lane] = fmaxf(acc1[i] + b1, 0.f);
  }
}

// ---------------- per-graph mean pool (batch is sorted) ----------------

__global__ __launch_bounds__(128) void pool_kernel(const float* __restrict__ H,
                                                   const int* __restrict__ batch,
                                                   float* __restrict__ pooled, int n) {
  int g = blockIdx.x >> 3;
  int sub = blockIdx.x & 7;
  int lo = lower_bound_i(batch, n, g);
  int hi = lower_bound_i(batch, n, g + 1);
  int cnt = hi - lo;
  if (cnt <= 0) return;
  int chunk = (cnt + 7) >> 3;
  int s = lo + sub * chunk;
  int e = min(hi, s + chunk);
  if (s >= e) return;
  float acc = 0.f;
  for (int nd = s; nd < e; ++nd) acc += H[(size_t)nd * 128 + threadIdx.x];
  atomicAdd(&pooled[g * 128 + threadIdx.x], acc);
}

// ---------------- final MLP: relu(pooled/cnt @ W1 + b1) @ W2 + b2 ----------------

__global__ __launch_bounds__(64) void mlp_kernel(const float* __restrict__ pooled,
                                                 const int* __restrict__ batch,
                                                 const float* __restrict__ W1,
                                                 const float* __restrict__ b1,
                                                 const float* __restrict__ W2,
                                                 const float* __restrict__ b2,
                                                 float* __restrict__ out, int n) {
  __shared__ float p[128];
  __shared__ float h1[64];
  int g = blockIdx.x, f = threadIdx.x;
  int lo = lower_bound_i(batch, n, g);
  int hi = lower_bound_i(batch, n, g + 1);
  float inv = (hi > lo) ? 1.0f / (float)(hi - lo) : 0.f;
  p[f]      = pooled[g * 128 + f] * inv;
  p[f + 64] = pooled[g * 128 + 64 + f] * inv;
  __syncthreads();
  float a = b1[f];
  #pragma unroll 8
  for (int k = 0; k < 128; ++k) a = fmaf(p[k], W1[k * 64 + f], a);
  a = fmaxf(a, 0.f);
  h1[f] = a;
  __syncthreads();
  float o = b2[f];
  #pragma unroll 8
  for (int k = 0; k < 64; ++k) o = fmaf(h1[k], W2[k * 64 + f], o);
  out[g * 64 + f] = o;
}

// ---------------- launch ----------------

extern "C" void kernel_launch(void* const* d_in, const int* in_sizes, int n_in,
                              void* d_out, int out_size, void* d_ws, size_t ws_size,
                              hipStream_t stream) {
  const float* x      = (const float*)d_in[0];
  const int*   edge   = (const int*)d_in[1];
  const int*   batch  = (const int*)d_in[2];
  const float* Wl1    = (const float*)d_in[3];
  const float* Wr1    = (const float*)d_in[4];
  const float* b1     = (const float*)d_in[5];
  const float* Wl2    = (const float*)d_in[6];
  const float* Wr2    = (const float*)d_in[7];
  const float* b2     = (const float*)d_in[8];
  const float* Wl3    = (const float*)d_in[9];
  const float* Wr3    = (const float*)d_in[10];
  const float* b3     = (const float*)d_in[11];
  const float* Wlin1  = (const float*)d_in[12];
  const float* blin1  = (const float*)d_in[13];
  const float* Wlin2  = (const float*)d_in[14];
  const float* blin2  = (const float*)d_in[15];
  float* out = (float*)d_out;

  const int* src = edge;        // edge_index[0]
  const int* dst = edge + NE;   // edge_index[1]

  // workspace carve-up (256B aligned)
  char* ws = (char*)d_ws;
  size_t off = 0;
  auto alloc = [&](size_t bytes) -> char* {
    char* p = ws + off;
    off = (off + bytes + 255) & ~(size_t)255;
    return p;
  };
  int*   deg    = (int*)alloc((size_t)NN * 4);
  int*   rs     = (int*)alloc((size_t)(NN + 1) * 4);
  int*   cur    = (int*)alloc((size_t)NN * 4);
  int*   col    = (int*)alloc((size_t)NE * 4);
  float* meanb  = (float*)alloc((size_t)NN * 128 * 4);
  float* hA     = (float*)alloc((size_t)NN * 128 * 4);
  float* hB     = (float*)alloc((size_t)NN * 128 * 4);
  float* pooled = (float*)alloc((size_t)NG * 128 * 4);
  (void)ws_size; (void)n_in; (void)in_sizes; (void)out_size;

  // 1) CSR build (edges are constant, but ws is re-poisoned every call)
  zero_kernel<<<(NN + 255) / 256, 256, 0, stream>>>(deg, pooled, NN, NG * 128);
  count_deg_kernel<<<(NE + 255) / 256, 256, 0, stream>>>(dst, deg, NE);
  scan_kernel<<<1, 1024, 0, stream>>>(deg, rs, NN);
  init_cursor_kernel<<<(NN + 255) / 256, 256, 0, stream>>>(rs, cur, NN);
  fill_csr_kernel<<<(NE + 255) / 256, 256, 0, stream>>>(src, dst, cur, col, NE);

  // 2) layer 1: aggregate x (d=64) -> mean ; hA = relu(mean@Wl1 + x@Wr1 + b1)
  aggregate64_kernel<<<(NN + 3) / 4, 256, 0, stream>>>(x, rs, col, meanb, NN);
  sage_gemm_kernel<64, 8><<<NN / 8, 64, 0, stream>>>(meanb, x, Wl1, Wr1, b1, hA);

  // 3) layer 2: aggregate hA (d=128) -> mean ; hB = relu(mean@Wl2 + hA@Wr2 + b2)
  aggregate128_kernel<<<(NN + 3) / 4, 256, 0, stream>>>(hA, rs, col, meanb, NN);
  sage_gemm_kernel<128, 8><<<NN / 8, 64, 0, stream>>>(meanb, hA, Wl2, Wr2, b2, hB);

  // 4) layer 3: aggregate hB -> mean ; hA = relu(mean@Wl3 + hB@Wr3 + b3)
  aggregate128_kernel<<<(NN + 3) / 4, 256, 0, stream>>>(hB, rs, col, meanb, NN);
  sage_gemm_kernel<128, 8><<<NN / 8, 64, 0, stream>>>(meanb, hB, Wl3, Wr3, b3, hA);

  // 5) per-graph mean pool + tiny MLP
  pool_kernel<<<NG * 8, 128, 0, stream>>>(hA, batch, pooled, NN);
  mlp_kernel<<<NG, 64, 0, stream>>>(pooled, batch, Wlin1, blin1, Wlin2, blin2, out, NN);
}

// Round 2
// 752.690 us; speedup vs baseline: 1.5946x; 1.5946x over previous
//
#include <hip/hip_runtime.h>
#include <hip/hip_bf16.h>
#include <cstdint>
#include <cstddef>

// Problem constants (match reference setup_inputs)
#define NN 100000     // nodes
#define NE 1600000    // edges
#define NG 64         // graphs
#define NPAD 100096   // NN padded to multiple of 128 (GEMM M-tile)
// IN=64, H=128, EMB=64

typedef short short8v __attribute__((ext_vector_type(8)));
typedef float float4v __attribute__((ext_vector_type(4)));

// ---------------- helpers ----------------

__device__ __forceinline__ int lower_bound_i(const int* __restrict__ a, int n, int v) {
  int lo = 0, hi = n;
  while (lo < hi) { int m = (lo + hi) >> 1; if (a[m] < v) lo = m + 1; else hi = m; }
  return lo;
}

__device__ __forceinline__ float bf2f(ushort u) {
  return __uint_as_float(((unsigned int)u) << 16);
}

__device__ __forceinline__ ushort f2bf(float f) {
  __hip_bfloat16 h = __float2bfloat16(f);   // RNE
  return *reinterpret_cast<ushort*>(&h);
}

// ---------------- CSR build ----------------

__global__ void zero_kernel(int* __restrict__ deg, float* __restrict__ pooled, int n, int np) {
  int i = blockIdx.x * blockDim.x + threadIdx.x;
  if (i < n) deg[i] = 0;
  if (i < np) pooled[i] = 0.f;
}

__global__ void count_deg_kernel(const int* __restrict__ dst, int* __restrict__ deg, int e) {
  int i = blockIdx.x * blockDim.x + threadIdx.x;
  if (i < e) atomicAdd(&deg[dst[i]], 1);
}

// multi-block exclusive scan, step 1: per-block scan + block totals
__global__ __launch_bounds__(1024) void scan1_kernel(const int* __restrict__ deg,
                                                     int* __restrict__ rs,
                                                     int* __restrict__ btot, int n) {
  __shared__ int wsum[16];
  int tid = threadIdx.x, lane = tid & 63, wid = tid >> 6;
  int i = blockIdx.x * 1024 + tid;
  int v = (i < n) ? deg[i] : 0;
  int incl = v;
  #pragma unroll
  for (int off = 1; off < 64; off <<= 1) {
    int t = __shfl_up(incl, off, 64);
    if (lane >= off) incl += t;
  }
  if (lane == 63) wsum[wid] = incl;
  __syncthreads();
  if (tid == 0) {
    int acc = 0;
    #pragma unroll
    for (int j = 0; j < 16; ++j) { int t = wsum[j]; wsum[j] = acc; acc += t; }
    btot[blockIdx.x] = acc;
  }
  __syncthreads();
  if (i < n) rs[i] = incl - v + wsum[wid];
}

// step 2: single block scans the (<=128) block totals
__global__ __launch_bounds__(128) void scan2_kernel(const int* __restrict__ btot,
                                                    int* __restrict__ boff, int nb) {
  __shared__ int ws2[2];
  int tid = threadIdx.x, lane = tid & 63, wid = tid >> 6;
  int v = (tid < nb) ? btot[tid] : 0;
  int incl = v;
  #pragma unroll
  for (int off = 1; off < 64; off <<= 1) {
    int t = __shfl_up(incl, off, 64);
    if (lane >= off) incl += t;
  }
  if (lane == 63) ws2[wid] = incl;
  __syncthreads();
  if (tid == 0) { int t0 = ws2[0]; ws2[0] = 0; ws2[1] = t0; }
  __syncthreads();
  if (tid < nb) boff[tid] = incl - v + ws2[wid];
}

// step 3: apply block offsets, init cursors, set rs[n]
__global__ void scan3_kernel(int* __restrict__ rs, const int* __restrict__ boff,
                             int* __restrict__ cur, int n) {
  int i = blockIdx.x * blockDim.x + threadIdx.x;
  if (i < n) {
    int val = rs[i] + boff[i >> 10];
    rs[i] = val;
    cur[i] = val;
  }
  if (i == 0) rs[n] = NE;
}

__global__ void fill_csr_kernel(const int* __restrict__ src, const int* __restrict__ dst,
                                int* __restrict__ cur, int* __restrict__ col, int e) {
  int i = blockIdx.x * blockDim.x + threadIdx.x;
  if (i < e) {
    int p = atomicAdd(&cur[dst[i]], 1);
    col[p] = src[i];
  }
}

// ---------------- dtype packing ----------------

// x fp32 [NN*64] -> bf16
__global__ void pack_x_kernel(const float* __restrict__ x, ushort* __restrict__ xb) {
  int i4 = blockIdx.x * blockDim.x + threadIdx.x;
  int idx = i4 * 4;
  if (idx >= NN * 64) return;
  float4 v = *(const float4*)(x + idx);
  ushort4 o;
  o.x = f2bf(v.x); o.y = f2bf(v.y); o.z = f2bf(v.z); o.w = f2bf(v.w);
  *(ushort4*)(xb + idx) = o;
}

// Pack [Wl;Wr] ([K x 128] each, fp32, row-major) into MFMA A-operand fragment order:
// Wp[((kkp*8 + ft)*64 + lane)*8 + j] = W{l|r}[k][ft*16 + (lane&15)] bf16,
// k = (kkp*32 + (lane>>4)*8 + j) mod K, source = kkp >= K/32.
__global__ void pack_w_kernel(const float* __restrict__ Wl, const float* __restrict__ Wr,
                              ushort* __restrict__ Wp, int K) {
  int idx = blockIdx.x * blockDim.x + threadIdx.x;
  int KS = K / 32;
  if (idx >= 2 * KS * 8 * 64) return;
  int lane = idx & 63;
  int ft   = (idx >> 6) & 7;
  int kkp  = idx >> 9;
  int kbase = kkp * 32 + (lane >> 4) * 8;
  int isR = kbase >= K;
  const float* W = isR ? Wr : Wl;
  int k0 = kbase - (isR ? K : 0);
  int colf = ft * 16 + (lane & 15);
  ushort4 lo, hi;
  lo.x = f2bf(W[(k0 + 0) * 128 + colf]);
  lo.y = f2bf(W[(k0 + 1) * 128 + colf]);
  lo.z = f2bf(W[(k0 + 2) * 128 + colf]);
  lo.w = f2bf(W[(k0 + 3) * 128 + colf]);
  hi.x = f2bf(W[(k0 + 4) * 128 + colf]);
  hi.y = f2bf(W[(k0 + 5) * 128 + colf]);
  hi.z = f2bf(W[(k0 + 6) * 128 + colf]);
  hi.w = f2bf(W[(k0 + 7) * 128 + colf]);
  *(ushort4*)(Wp + (size_t)idx * 8)     = lo;
  *(ushort4*)(Wp + (size_t)idx * 8 + 4) = hi;
}

// ---------------- mean aggregation (gather over CSR, bf16 features) ----------------

__global__ __launch_bounds__(256) void agg64b_kernel(const ushort* __restrict__ X,
                                                     const int* __restrict__ rs,
                                                     const int* __restrict__ col,
                                                     ushort* __restrict__ out, int n) {
  int lane = threadIdx.x & 63;
  int node = blockIdx.x * 4 + (threadIdx.x >> 6);
  if (node >= n) return;
  int a = rs[node], b = rs[node + 1];
  float acc = 0.f;
  for (int jb = a; jb < b; jb += 64) {
    int v = 0;
    if (jb + lane < b) v = col[jb + lane];
    int cnt = min(64, b - jb);
    for (int t = 0; t < cnt; ++t) {
      int s = __shfl(v, t, 64);
      acc += bf2f(X[(size_t)s * 64 + lane]);
    }
  }
  int d = b - a;
  float inv = d > 0 ? 1.0f / (float)d : 0.f;
  out[(size_t)node * 64 + lane] = f2bf(acc * inv);
}

__global__ __launch_bounds__(256) void agg128b_kernel(const ushort* __restrict__ X,
                                                      const int* __restrict__ rs,
                                                      const int* __restrict__ col,
                                                      ushort* __restrict__ out, int n) {
  int lane = threadIdx.x & 63;
  int node = blockIdx.x * 4 + (threadIdx.x >> 6);
  if (node >= n) return;
  int a = rs[node], b = rs[node + 1];
  const unsigned int* __restrict__ Xu = (const unsigned int*)X;
  float ax = 0.f, ay = 0.f;
  for (int jb = a; jb < b; jb += 64) {
    int v = 0;
    if (jb + lane < b) v = col[jb + lane];
    int cnt = min(64, b - jb);
    for (int t = 0; t < cnt; ++t) {
      int s = __shfl(v, t, 64);
      unsigned int u = Xu[(size_t)s * 64 + lane];
      ax += __uint_as_float(u << 16);
      ay += __uint_as_float(u & 0xffff0000u);
    }
  }
  int d = b - a;
  float inv = d > 0 ? 1.0f / (float)d : 0.f;
  unsigned int o = (unsigned int)f2bf(ax * inv) | ((unsigned int)f2bf(ay * inv) << 16);
  ((unsigned int*)out)[(size_t)node * 64 + lane] = o;
}

// ---------------- MFMA SAGE GEMM: Out = relu([Mean|X] @ [Wl;Wr] + b), bf16 ----------------
// Computes C^T: A-operand = packed weights (lane&15 = output feature), B-operand =
// activations (lane&15 = node, 8 contiguous k per lane from row-major bf16 rows).
// D frag: col(lane&15)=node, row(quad*4+r)=feature -> 4 consecutive features of one
// node per lane -> 8-byte packed bf16 stores. Block = 4 waves, 32 nodes/wave.

template <int K>
__global__ __launch_bounds__(256) void mfma_gemm_kernel(const ushort* __restrict__ Mean,
                                                        const ushort* __restrict__ Xb,
                                                        const ushort* __restrict__ Wp,
                                                        const float* __restrict__ bias,
                                                        ushort* __restrict__ Out) {
  constexpr int KS = K / 32;
  int lane = threadIdx.x & 63;
  int wave = threadIdx.x >> 6;
  int quad = lane >> 4;
  int l16  = lane & 15;
  size_t node0 = (size_t)blockIdx.x * 128 + wave * 32;

  float4v acc[2][8];
  #pragma unroll
  for (int g = 0; g < 2; ++g)
    #pragma unroll
    for (int ft = 0; ft < 8; ++ft)
      acc[g][ft] = (float4v){0.f, 0.f, 0.f, 0.f};

  #pragma unroll
  for (int s = 0; s < 2; ++s) {
    const ushort* __restrict__ A = s ? Xb : Mean;
    #pragma unroll
    for (int kk = 0; kk < KS; ++kk) {
      int kkp = s * KS + kk;
      // weight fragments (A-operand), fully coalesced from packed buffer
      short8v wv[8];
      const ushort* wb = Wp + ((size_t)(kkp * 8) * 64 + lane) * 8;
      #pragma unroll
      for (int ft = 0; ft < 8; ++ft)
        wv[ft] = *(const short8v*)(wb + (size_t)ft * 64 * 8);
      // activation fragments (B-operand)
      short8v av[2];
      #pragma unroll
      for (int g = 0; g < 2; ++g)
        av[g] = *(const short8v*)(A + (node0 + g * 16 + l16) * K + kk * 32 + quad * 8);
      #pragma unroll
      for (int g = 0; g < 2; ++g)
        #pragma unroll
        for (int ft = 0; ft < 8; ++ft)
          acc[g][ft] = __builtin_amdgcn_mfma_f32_16x16x32_bf16(wv[ft], av[g], acc[g][ft], 0, 0, 0);
    }
  }

  #pragma unroll
  for (int g = 0; g < 2; ++g) {
    size_t nrow = node0 + g * 16 + l16;
    #pragma unroll
    for (int ft = 0; ft < 8; ++ft) {
      float4 bb = *(const float4*)(bias + ft * 16 + quad * 4);
      float4v v = acc[g][ft];
      ushort4 o;
      o.x = f2bf(fmaxf(v.x + bb.x, 0.f));
      o.y = f2bf(fmaxf(v.y + bb.y, 0.f));
      o.z = f2bf(fmaxf(v.z + bb.z, 0.f));
      o.w = f2bf(fmaxf(v.w + bb.w, 0.f));
      *(ushort4*)(Out + nrow * 128 + ft * 16 + quad * 4) = o;
    }
  }
}

// ---------------- per-graph mean pool (batch sorted, bf16 input) ----------------

__global__ __launch_bounds__(128) void pool_kernel(const ushort* __restrict__ H,
                                                   const int* __restrict__ batch,
                                                   float* __restrict__ pooled, int n) {
  int g = blockIdx.x >> 3;
  int sub = blockIdx.x & 7;
  int lo = lower_bound_i(batch, n, g);
  int hi = lower_bound_i(batch, n, g + 1);
  int cnt = hi - lo;
  if (cnt <= 0) return;
  int chunk = (cnt + 7) >> 3;
  int s = lo + sub * chunk;
  int e = min(hi, s + chunk);
  if (s >= e) return;
  float acc = 0.f;
  for (int nd = s; nd < e; ++nd) acc += bf2f(H[(size_t)nd * 128 + threadIdx.x]);
  atomicAdd(&pooled[g * 128 + threadIdx.x], acc);
}

// ---------------- final MLP: relu(pooled/cnt @ W1 + b1) @ W2 + b2 (fp32) ----------------

__global__ __launch_bounds__(64) void mlp_kernel(const float* __restrict__ pooled,
                                                 const int* __restrict__ batch,
                                                 const float* __restrict__ W1,
                                                 const float* __restrict__ b1,
                                                 const float* __restrict__ W2,
                                                 const float* __restrict__ b2,
                                                 float* __restrict__ out, int n) {
  __shared__ float p[128];
  __shared__ float h1[64];
  int g = blockIdx.x, f = threadIdx.x;
  int lo = lower_bound_i(batch, n, g);
  int hi = lower_bound_i(batch, n, g + 1);
  float inv = (hi > lo) ? 1.0f / (float)(hi - lo) : 0.f;
  p[f]      = pooled[g * 128 + f] * inv;
  p[f + 64] = pooled[g * 128 + 64 + f] * inv;
  __syncthreads();
  float a = b1[f];
  #pragma unroll 8
  for (int k = 0; k < 128; ++k) a = fmaf(p[k], W1[k * 64 + f], a);
  a = fmaxf(a, 0.f);
  h1[f] = a;
  __syncthreads();
  float o = b2[f];
  #pragma unroll 8
  for (int k = 0; k < 64; ++k) o = fmaf(h1[k], W2[k * 64 + f], o);
  out[g * 64 + f] = o;
}

// ---------------- launch ----------------

extern "C" void kernel_launch(void* const* d_in, const int* in_sizes, int n_in,
                              void* d_out, int out_size, void* d_ws, size_t ws_size,
                              hipStream_t stream) {
  const float* x      = (const float*)d_in[0];
  const int*   edge   = (const int*)d_in[1];
  const int*   batch  = (const int*)d_in[2];
  const float* Wl1    = (const float*)d_in[3];
  const float* Wr1    = (const float*)d_in[4];
  const float* b1     = (const float*)d_in[5];
  const float* Wl2    = (const float*)d_in[6];
  const float* Wr2    = (const float*)d_in[7];
  const float* b2     = (const float*)d_in[8];
  const float* Wl3    = (const float*)d_in[9];
  const float* Wr3    = (const float*)d_in[10];
  const float* b3     = (const float*)d_in[11];
  const float* Wlin1  = (const float*)d_in[12];
  const float* blin1  = (const float*)d_in[13];
  const float* Wlin2  = (const float*)d_in[14];
  const float* blin2  = (const float*)d_in[15];
  float* out = (float*)d_out;

  const int* src = edge;        // edge_index[0]
  const int* dst = edge + NE;   // edge_index[1]

  // workspace carve-up (256B aligned)
  char* ws = (char*)d_ws;
  size_t off = 0;
  auto alloc = [&](size_t bytes) -> char* {
    char* p = ws + off;
    off = (off + bytes + 255) & ~(size_t)255;
    return p;
  };
  int*    deg    = (int*)alloc((size_t)NN * 4);
  int*    rs     = (int*)alloc((size_t)(NN + 1) * 4);
  int*    cur    = (int*)alloc((size_t)NN * 4);
  int*    col    = (int*)alloc((size_t)NE * 4);
  int*    btot   = (int*)alloc(128 * 4);
  int*    boff   = (int*)alloc(128 * 4);
  ushort* xb     = (ushort*)alloc((size_t)NPAD * 64 * 2);
  ushort* mean64 = (ushort*)alloc((size_t)NPAD * 64 * 2);
  ushort* mean128= (ushort*)alloc((size_t)NPAD * 128 * 2);
  ushort* h1     = (ushort*)alloc((size_t)NPAD * 128 * 2);
  ushort* h2     = (ushort*)alloc((size_t)NPAD * 128 * 2);
  ushort* h3     = (ushort*)alloc((size_t)NPAD * 128 * 2);
  ushort* wp1    = (ushort*)alloc((size_t)2 * 64 * 128 * 2);   // [2K=128 x 128]
  ushort* wp2    = (ushort*)alloc((size_t)2 * 128 * 128 * 2);  // [2K=256 x 128]
  ushort* wp3    = (ushort*)alloc((size_t)2 * 128 * 128 * 2);
  float*  pooled = (float*)alloc((size_t)NG * 128 * 4);
  (void)ws_size; (void)n_in; (void)in_sizes; (void)out_size;

  const int NB = (NN + 1023) / 1024;  // 98 scan blocks

  // 1) CSR build + dtype packs (packs are independent of CSR)
  zero_kernel<<<(NN + 255) / 256, 256, 0, stream>>>(deg, pooled, NN, NG * 128);
  pack_x_kernel<<<(NN * 64 / 4 + 255) / 256, 256, 0, stream>>>(x, xb);
  pack_w_kernel<<<(2 * 2 * 8 * 64 + 255) / 256, 256, 0, stream>>>(Wl1, Wr1, wp1, 64);
  pack_w_kernel<<<(2 * 4 * 8 * 64 + 255) / 256, 256, 0, stream>>>(Wl2, Wr2, wp2, 128);
  pack_w_kernel<<<(2 * 4 * 8 * 64 + 255) / 256, 256, 0, stream>>>(Wl3, Wr3, wp3, 128);
  count_deg_kernel<<<(NE + 255) / 256, 256, 0, stream>>>(dst, deg, NE);
  scan1_kernel<<<NB, 1024, 0, stream>>>(deg, rs, btot, NN);
  scan2_kernel<<<1, 128, 0, stream>>>(btot, boff, NB);
  scan3_kernel<<<(NN + 255) / 256, 256, 0, stream>>>(rs, boff, cur, NN);
  fill_csr_kernel<<<(NE + 255) / 256, 256, 0, stream>>>(src, dst, cur, col, NE);

  // 2) layer 1: mean(xb) -> h1 = relu([mean|xb] @ [Wl1;Wr1] + b1)
  agg64b_kernel<<<(NN + 3) / 4, 256, 0, stream>>>(xb, rs, col, mean64, NN);
  mfma_gemm_kernel<64><<<NPAD / 128, 256, 0, stream>>>(mean64, xb, wp1, b1, h1);

  // 3) layer 2
  agg128b_kernel<<<(NN + 3) / 4, 256, 0, stream>>>(h1, rs, col, mean128, NN);
  mfma_gemm_kernel<128><<<NPAD / 128, 256, 0, stream>>>(mean128, h1, wp2, b2, h2);

  // 4) layer 3
  agg128b_kernel<<<(NN + 3) / 4, 256, 0, stream>>>(h2, rs, col, mean128, NN);
  mfma_gemm_kernel<128><<<NPAD / 128, 256, 0, stream>>>(mean128, h2, wp3, b3, h3);

  // 5) per-graph mean pool + tiny MLP (fp32)
  pool_kernel<<<NG * 8, 128, 0, stream>>>(h3, batch, pooled, NN);
  mlp_kernel<<<NG, 64, 0, stream>>>(pooled, batch, Wlin1, blin1, Wlin2, blin2, out, NN);
}

// Round 3
// 460.800 us; speedup vs baseline: 2.6046x; 1.6334x over previous
//
#include <hip/hip_runtime.h>
#include <hip/hip_bf16.h>
#include <cstdint>
#include <cstddef>

// Problem constants (match reference setup_inputs)
#define NN 100000     // nodes
#define NE 1600000    // edges
#define NG 64         // graphs
#define NPAD 100096   // NN padded to multiple of 128 (GEMM M-tile)
#define NBUK 782      // dst-buckets of 128 nodes: (NN+127)>>7
#define CAP 3072      // padded bucket capacity (expected 2046, sigma~45 -> 22 sigma)
#define NFB 512       // bucket_fill blocks
#define CHUNK 3125    // edges per fill block (NFB*CHUNK == NE)

typedef short short8v __attribute__((ext_vector_type(8)));
typedef float float4v __attribute__((ext_vector_type(4)));

// ---------------- helpers ----------------

__device__ __forceinline__ int lower_bound_i(const int* __restrict__ a, int n, int v) {
  int lo = 0, hi = n;
  while (lo < hi) { int m = (lo + hi) >> 1; if (a[m] < v) lo = m + 1; else hi = m; }
  return lo;
}

__device__ __forceinline__ float bf2f(ushort u) {
  return __uint_as_float(((unsigned int)u) << 16);
}

__device__ __forceinline__ ushort f2bf(float f) {
  __hip_bfloat16 h = __float2bfloat16(f);   // RNE
  return *reinterpret_cast<ushort*>(&h);
}

// ---------------- dtype packing ----------------

// x fp32 [NN*64] -> bf16; also init bucket cursors (runs before bucket_fill)
__global__ void pack_x_kernel(const float* __restrict__ x, ushort* __restrict__ xb,
                              int* __restrict__ bcur) {
  int i4 = blockIdx.x * blockDim.x + threadIdx.x;
  if (i4 < NBUK) bcur[i4] = i4 * CAP;
  int idx = i4 * 4;
  if (idx >= NN * 64) return;
  float4 v = *(const float4*)(x + idx);
  ushort4 o;
  o.x = f2bf(v.x); o.y = f2bf(v.y); o.z = f2bf(v.z); o.w = f2bf(v.w);
  *(ushort4*)(xb + idx) = o;
}

// Pack [Wl;Wr] ([K x 128] each, fp32, row-major) into MFMA A-operand fragment order.
__device__ __forceinline__ void pack_one(const float* __restrict__ Wl,
                                         const float* __restrict__ Wr,
                                         ushort* __restrict__ Wp, int K, int idx) {
  int lane = idx & 63;
  int ft   = (idx >> 6) & 7;
  int kkp  = idx >> 9;
  int kbase = kkp * 32 + (lane >> 4) * 8;
  int isR = kbase >= K;
  const float* W = isR ? Wr : Wl;
  int k0 = kbase - (isR ? K : 0);
  int colf = ft * 16 + (lane & 15);
  ushort4 lo, hi;
  lo.x = f2bf(W[(k0 + 0) * 128 + colf]);
  lo.y = f2bf(W[(k0 + 1) * 128 + colf]);
  lo.z = f2bf(W[(k0 + 2) * 128 + colf]);
  lo.w = f2bf(W[(k0 + 3) * 128 + colf]);
  hi.x = f2bf(W[(k0 + 4) * 128 + colf]);
  hi.y = f2bf(W[(k0 + 5) * 128 + colf]);
  hi.z = f2bf(W[(k0 + 6) * 128 + colf]);
  hi.w = f2bf(W[(k0 + 7) * 128 + colf]);
  *(ushort4*)(Wp + (size_t)idx * 8)     = lo;
  *(ushort4*)(Wp + (size_t)idx * 8 + 4) = hi;
}

__global__ void pack_w_all_kernel(const float* __restrict__ Wl1, const float* __restrict__ Wr1,
                                  ushort* __restrict__ wp1,
                                  const float* __restrict__ Wl2, const float* __restrict__ Wr2,
                                  ushort* __restrict__ wp2,
                                  const float* __restrict__ Wl3, const float* __restrict__ Wr3,
                                  ushort* __restrict__ wp3) {
  int idx = blockIdx.x * blockDim.x + threadIdx.x;
  if (idx < 2048)       pack_one(Wl1, Wr1, wp1, 64,  idx);
  else if (idx < 6144)  pack_one(Wl2, Wr2, wp2, 128, idx - 2048);
  else if (idx < 10240) pack_one(Wl3, Wr3, wp3, 128, idx - 6144);
}

// ---------------- CSR build: two-level multisplit ----------------

// Phase 1: partition edges into padded dst-buckets. Per-block LDS histogram,
// one range-reservation atomic per (block,bucket), dense appended writes.
__global__ __launch_bounds__(256) void bucket_fill_kernel(const int* __restrict__ src,
                                                          const int* __restrict__ dst,
                                                          int* __restrict__ bcur,
                                                          unsigned int* __restrict__ bp) {
  __shared__ int lhist[NBUK];
  __shared__ int lbase[NBUK];
  int tid = threadIdx.x;
  int e0 = blockIdx.x * CHUNK;
  int e1 = e0 + CHUNK;   // NFB*CHUNK == NE exactly
  for (int i = tid; i < NBUK; i += 256) lhist[i] = 0;
  __syncthreads();
  for (int i = e0 + tid; i < e1; i += 256) atomicAdd(&lhist[dst[i] >> 7], 1);
  __syncthreads();
  for (int b = tid; b < NBUK; b += 256) {
    int c = lhist[b];
    lbase[b] = c ? atomicAdd(&bcur[b], c) : 0;
    lhist[b] = 0;   // reuse as local cursor
  }
  __syncthreads();
  for (int i = e0 + tid; i < e1; i += 256) {
    int d = dst[i];
    int b = d >> 7;
    int p = atomicAdd(&lhist[b], 1);
    int pos = lbase[b] + p;
    if (pos < (b + 1) * CAP)   // overflow guard (never triggers at CAP=3072)
      bp[pos] = ((unsigned int)(d & 127) << 17) | (unsigned int)src[i];
  }
}

// Phase 2: scan bucket counts -> boff (CSR bucket bases); also zero pooled, rs[NN].
__global__ __launch_bounds__(1024) void bucket_scan_kernel(const int* __restrict__ bcur,
                                                           int* __restrict__ boff,
                                                           int* __restrict__ rs,
                                                           float* __restrict__ pooled) {
  __shared__ int wsum[16];
  int tid = threadIdx.x, lane = tid & 63, wid = tid >> 6;
  int v = 0;
  if (tid < NBUK) v = min(bcur[tid] - tid * CAP, CAP);
  int incl = v;
  #pragma unroll
  for (int off = 1; off < 64; off <<= 1) {
    int t = __shfl_up(incl, off, 64);
    if (lane >= off) incl += t;
  }
  if (lane == 63) wsum[wid] = incl;
  __syncthreads();
  if (tid == 0) {
    int acc = 0;
    #pragma unroll
    for (int j = 0; j < 16; ++j) { int t = wsum[j]; wsum[j] = acc; acc += t; }
  }
  __syncthreads();
  int excl = incl - v + wsum[wid];
  if (tid <= NBUK) boff[tid] = excl;   // boff[NBUK] = NE (v==0 past end)
  for (int i = tid; i < NG * 128; i += 1024) pooled[i] = 0.f;
  if (tid == 0) rs[NN] = NE;
}

// Phase 3: one workgroup per bucket builds its CSR slice in LDS; col writes
// land in a contiguous L2-resident window.
__global__ __launch_bounds__(256) void bucket_csr_kernel(const unsigned int* __restrict__ bp,
                                                         const int* __restrict__ boff,
                                                         int* __restrict__ rs,
                                                         int* __restrict__ col) {
  __shared__ int sdeg[128], sinc[128], lcur[128];
  int b = blockIdx.x, tid = threadIdx.x;
  int n0 = b << 7;
  int e0 = boff[b], e1 = boff[b + 1];
  int cnt = e1 - e0;
  const unsigned int* __restrict__ mybp = bp + (size_t)b * CAP;
  if (tid < 128) sdeg[tid] = 0;
  __syncthreads();
  for (int i = tid; i < cnt; i += 256) atomicAdd(&sdeg[mybp[i] >> 17], 1);
  __syncthreads();
  if (tid < 128) sinc[tid] = sdeg[tid];
  __syncthreads();
  #pragma unroll
  for (int off = 1; off < 128; off <<= 1) {
    int add = 0;
    if (tid < 128 && tid >= off) add = sinc[tid - off];
    __syncthreads();
    if (tid < 128) sinc[tid] += add;
    __syncthreads();
  }
  if (tid < 128) {
    int excl = sinc[tid] - sdeg[tid];
    lcur[tid] = excl;
    int node = n0 + tid;
    if (node < NN) rs[node] = e0 + excl;
  }
  __syncthreads();
  for (int i = tid; i < cnt; i += 256) {
    unsigned int v = mybp[i];
    int p = atomicAdd(&lcur[v >> 17], 1);
    col[e0 + p] = (int)(v & 0x1FFFF);
  }
}

// ---------------- mean aggregation (gather over CSR, bf16, uint4 loads) ----------------
// d=64: rows are 32 uints (128B); 8 lanes x 16B per row -> 8 neighbors per load instr.

__global__ __launch_bounds__(256) void agg64_kernel(const unsigned int* __restrict__ X,
                                                    const int* __restrict__ rs,
                                                    const int* __restrict__ col,
                                                    unsigned int* __restrict__ out, int n) {
  int lane = threadIdx.x & 63;
  int node = blockIdx.x * 4 + (threadIdx.x >> 6);
  if (node >= n) return;
  int a = rs[node], b = rs[node + 1];
  int grp = lane >> 3, fl = lane & 7;
  float acc[8];
  #pragma unroll
  for (int j = 0; j < 8; ++j) acc[j] = 0.f;
  for (int jb = a; jb < b; jb += 64) {
    int v = (jb + lane < b) ? col[jb + lane] : 0;
    int cnt = min(64, b - jb);
    for (int t = 0; t < cnt; t += 8) {
      int idx = t + grp;
      int s = __shfl(v, min(idx, cnt - 1), 64);
      uint4 u = *(const uint4*)(X + (size_t)s * 32 + fl * 4);
      if (idx < cnt) {
        acc[0] += __uint_as_float(u.x << 16);
        acc[1] += __uint_as_float(u.x & 0xffff0000u);
        acc[2] += __uint_as_float(u.y << 16);
        acc[3] += __uint_as_float(u.y & 0xffff0000u);
        acc[4] += __uint_as_float(u.z << 16);
        acc[5] += __uint_as_float(u.z & 0xffff0000u);
        acc[6] += __uint_as_float(u.w << 16);
        acc[7] += __uint_as_float(u.w & 0xffff0000u);
      }
    }
  }
  #pragma unroll
  for (int off = 8; off <= 32; off <<= 1)
    #pragma unroll
    for (int j = 0; j < 8; ++j) acc[j] += __shfl_xor(acc[j], off, 64);
  int d = b - a;
  float inv = d > 0 ? 1.0f / (float)d : 0.f;
  if (grp == 0) {
    uint4 o;
    o.x = (unsigned int)f2bf(acc[0] * inv) | ((unsigned int)f2bf(acc[1] * inv) << 16);
    o.y = (unsigned int)f2bf(acc[2] * inv) | ((unsigned int)f2bf(acc[3] * inv) << 16);
    o.z = (unsigned int)f2bf(acc[4] * inv) | ((unsigned int)f2bf(acc[5] * inv) << 16);
    o.w = (unsigned int)f2bf(acc[6] * inv) | ((unsigned int)f2bf(acc[7] * inv) << 16);
    *(uint4*)(out + (size_t)node * 32 + fl * 4) = o;
  }
}

// d=128: rows are 64 uints (256B); 16 lanes x 16B per row -> 4 neighbors per load instr.
__global__ __launch_bounds__(256) void agg128_kernel(const unsigned int* __restrict__ X,
                                                     const int* __restrict__ rs,
                                                     const int* __restrict__ col,
                                                     unsigned int* __restrict__ out, int n) {
  int lane = threadIdx.x & 63;
  int node = blockIdx.x * 4 + (threadIdx.x >> 6);
  if (node >= n) return;
  int a = rs[node], b = rs[node + 1];
  int grp = lane >> 4, fl = lane & 15;
  float acc[8];
  #pragma unroll
  for (int j = 0; j < 8; ++j) acc[j] = 0.f;
  for (int jb = a; jb < b; jb += 64) {
    int v = (jb + lane < b) ? col[jb + lane] : 0;
    int cnt = min(64, b - jb);
    for (int t = 0; t < cnt; t += 4) {
      int idx = t + grp;
      int s = __shfl(v, min(idx, cnt - 1), 64);
      uint4 u = *(const uint4*)(X + (size_t)s * 64 + fl * 4);
      if (idx < cnt) {
        acc[0] += __uint_as_float(u.x << 16);
        acc[1] += __uint_as_float(u.x & 0xffff0000u);
        acc[2] += __uint_as_float(u.y << 16);
        acc[3] += __uint_as_float(u.y & 0xffff0000u);
        acc[4] += __uint_as_float(u.z << 16);
        acc[5] += __uint_as_float(u.z & 0xffff0000u);
        acc[6] += __uint_as_float(u.w << 16);
        acc[7] += __uint_as_float(u.w & 0xffff0000u);
      }
    }
  }
  #pragma unroll
  for (int off = 16; off <= 32; off <<= 1)
    #pragma unroll
    for (int j = 0; j < 8; ++j) acc[j] += __shfl_xor(acc[j], off, 64);
  int d = b - a;
  float inv = d > 0 ? 1.0f / (float)d : 0.f;
  if (grp == 0) {
    uint4 o;
    o.x = (unsigned int)f2bf(acc[0] * inv) | ((unsigned int)f2bf(acc[1] * inv) << 16);
    o.y = (unsigned int)f2bf(acc[2] * inv) | ((unsigned int)f2bf(acc[3] * inv) << 16);
    o.z = (unsigned int)f2bf(acc[4] * inv) | ((unsigned int)f2bf(acc[5] * inv) << 16);
    o.w = (unsigned int)f2bf(acc[6] * inv) | ((unsigned int)f2bf(acc[7] * inv) << 16);
    *(uint4*)(out + (size_t)node * 64 + fl * 4) = o;
  }
}

// ---------------- MFMA SAGE GEMM: Out = relu([Mean|X] @ [Wl;Wr] + b), bf16 ----------------

template <int K>
__global__ __launch_bounds__(256) void mfma_gemm_kernel(const ushort* __restrict__ Mean,
                                                        const ushort* __restrict__ Xb,
                                                        const ushort* __restrict__ Wp,
                                                        const float* __restrict__ bias,
                                                        ushort* __restrict__ Out) {
  constexpr int KS = K / 32;
  int lane = threadIdx.x & 63;
  int wave = threadIdx.x >> 6;
  int quad = lane >> 4;
  int l16  = lane & 15;
  size_t node0 = (size_t)blockIdx.x * 128 + wave * 32;

  float4v acc[2][8];
  #pragma unroll
  for (int g = 0; g < 2; ++g)
    #pragma unroll
    for (int ft = 0; ft < 8; ++ft)
      acc[g][ft] = (float4v){0.f, 0.f, 0.f, 0.f};

  #pragma unroll
  for (int s = 0; s < 2; ++s) {
    const ushort* __restrict__ A = s ? Xb : Mean;
    #pragma unroll
    for (int kk = 0; kk < KS; ++kk) {
      int kkp = s * KS + kk;
      short8v wv[8];
      const ushort* wb = Wp + ((size_t)(kkp * 8) * 64 + lane) * 8;
      #pragma unroll
      for (int ft = 0; ft < 8; ++ft)
        wv[ft] = *(const short8v*)(wb + (size_t)ft * 64 * 8);
      short8v av[2];
      #pragma unroll
      for (int g = 0; g < 2; ++g)
        av[g] = *(const short8v*)(A + (node0 + g * 16 + l16) * K + kk * 32 + quad * 8);
      #pragma unroll
      for (int g = 0; g < 2; ++g)
        #pragma unroll
        for (int ft = 0; ft < 8; ++ft)
          acc[g][ft] = __builtin_amdgcn_mfma_f32_16x16x32_bf16(wv[ft], av[g], acc[g][ft], 0, 0, 0);
    }
  }

  #pragma unroll
  for (int g = 0; g < 2; ++g) {
    size_t nrow = node0 + g * 16 + l16;
    #pragma unroll
    for (int ft = 0; ft < 8; ++ft) {
      float4 bb = *(const float4*)(bias + ft * 16 + quad * 4);
      float4v v = acc[g][ft];
      ushort4 o;
      o.x = f2bf(fmaxf(v.x + bb.x, 0.f));
      o.y = f2bf(fmaxf(v.y + bb.y, 0.f));
      o.z = f2bf(fmaxf(v.z + bb.z, 0.f));
      o.w = f2bf(fmaxf(v.w + bb.w, 0.f));
      *(ushort4*)(Out + nrow * 128 + ft * 16 + quad * 4) = o;
    }
  }
}

// ---------------- per-graph mean pool (batch sorted, bf16 input) ----------------

__global__ __launch_bounds__(128) void pool_kernel(const ushort* __restrict__ H,
                                                   const int* __restrict__ batch,
                                                   float* __restrict__ pooled, int n) {
  int g = blockIdx.x >> 3;
  int sub = blockIdx.x & 7;
  int lo = lower_bound_i(batch, n, g);
  int hi = lower_bound_i(batch, n, g + 1);
  int cnt = hi - lo;
  if (cnt <= 0) return;
  int chunk = (cnt + 7) >> 3;
  int s = lo + sub * chunk;
  int e = min(hi, s + chunk);
  if (s >= e) return;
  float acc = 0.f;
  for (int nd = s; nd < e; ++nd) acc += bf2f(H[(size_t)nd * 128 + threadIdx.x]);
  atomicAdd(&pooled[g * 128 + threadIdx.x], acc);
}

// ---------------- final MLP: relu(pooled/cnt @ W1 + b1) @ W2 + b2 (fp32) ----------------

__global__ __launch_bounds__(64) void mlp_kernel(const float* __restrict__ pooled,
                                                 const int* __restrict__ batch,
                                                 const float* __restrict__ W1,
                                                 const float* __restrict__ b1,
                                                 const float* __restrict__ W2,
                                                 const float* __restrict__ b2,
                                                 float* __restrict__ out, int n) {
  __shared__ float p[128];
  __shared__ float h1[64];
  int g = blockIdx.x, f = threadIdx.x;
  int lo = lower_bound_i(batch, n, g);
  int hi = lower_bound_i(batch, n, g + 1);
  float inv = (hi > lo) ? 1.0f / (float)(hi - lo) : 0.f;
  p[f]      = pooled[g * 128 + f] * inv;
  p[f + 64] = pooled[g * 128 + 64 + f] * inv;
  __syncthreads();
  float a = b1[f];
  #pragma unroll 8
  for (int k = 0; k < 128; ++k) a = fmaf(p[k], W1[k * 64 + f], a);
  a = fmaxf(a, 0.f);
  h1[f] = a;
  __syncthreads();
  float o = b2[f];
  #pragma unroll 8
  for (int k = 0; k < 64; ++k) o = fmaf(h1[k], W2[k * 64 + f], o);
  out[g * 64 + f] = o;
}

// ---------------- launch ----------------

extern "C" void kernel_launch(void* const* d_in, const int* in_sizes, int n_in,
                              void* d_out, int out_size, void* d_ws, size_t ws_size,
                              hipStream_t stream) {
  const float* x      = (const float*)d_in[0];
  const int*   edge   = (const int*)d_in[1];
  const int*   batch  = (const int*)d_in[2];
  const float* Wl1    = (const float*)d_in[3];
  const float* Wr1    = (const float*)d_in[4];
  const float* b1     = (const float*)d_in[5];
  const float* Wl2    = (const float*)d_in[6];
  const float* Wr2    = (const float*)d_in[7];
  const float* b2     = (const float*)d_in[8];
  const float* Wl3    = (const float*)d_in[9];
  const float* Wr3    = (const float*)d_in[10];
  const float* b3     = (const float*)d_in[11];
  const float* Wlin1  = (const float*)d_in[12];
  const float* blin1  = (const float*)d_in[13];
  const float* Wlin2  = (const float*)d_in[14];
  const float* blin2  = (const float*)d_in[15];
  float* out = (float*)d_out;

  const int* src = edge;        // edge_index[0]
  const int* dst = edge + NE;   // edge_index[1]

  // workspace carve-up (256B aligned)
  char* ws = (char*)d_ws;
  size_t off = 0;
  auto alloc = [&](size_t bytes) -> char* {
    char* p = ws + off;
    off = (off + bytes + 255) & ~(size_t)255;
    return p;
  };
  int*    rs     = (int*)alloc((size_t)(NN + 1) * 4);
  int*    col    = (int*)alloc((size_t)NE * 4);
  int*    bcur   = (int*)alloc((size_t)NBUK * 4);
  int*    boff   = (int*)alloc((size_t)(NBUK + 1) * 4);
  unsigned int* bp = (unsigned int*)alloc((size_t)NBUK * CAP * 4);
  ushort* xb     = (ushort*)alloc((size_t)NPAD * 64 * 2);
  ushort* mean64 = (ushort*)alloc((size_t)NPAD * 64 * 2);
  ushort* mean128= (ushort*)alloc((size_t)NPAD * 128 * 2);
  ushort* h1     = (ushort*)alloc((size_t)NPAD * 128 * 2);
  ushort* h2     = (ushort*)alloc((size_t)NPAD * 128 * 2);
  ushort* h3     = (ushort*)alloc((size_t)NPAD * 128 * 2);
  ushort* wp1    = (ushort*)alloc((size_t)2 * 64 * 128 * 2);
  ushort* wp2    = (ushort*)alloc((size_t)2 * 128 * 128 * 2);
  ushort* wp3    = (ushort*)alloc((size_t)2 * 128 * 128 * 2);
  float*  pooled = (float*)alloc((size_t)NG * 128 * 4);
  (void)ws_size; (void)n_in; (void)in_sizes; (void)out_size;

  // 1) packs + CSR build (multisplit)
  pack_x_kernel<<<(NN * 64 / 4 + 255) / 256, 256, 0, stream>>>(x, xb, bcur);
  pack_w_all_kernel<<<40, 256, 0, stream>>>(Wl1, Wr1, wp1, Wl2, Wr2, wp2, Wl3, Wr3, wp3);
  bucket_fill_kernel<<<NFB, 256, 0, stream>>>(src, dst, bcur, bp);
  bucket_scan_kernel<<<1, 1024, 0, stream>>>(bcur, boff, rs, pooled);
  bucket_csr_kernel<<<NBUK, 256, 0, stream>>>(bp, boff, rs, col);

  // 2) layer 1
  agg64_kernel<<<(NN + 3) / 4, 256, 0, stream>>>((const unsigned int*)xb, rs, col,
                                                 (unsigned int*)mean64, NN);
  mfma_gemm_kernel<64><<<NPAD / 128, 256, 0, stream>>>(mean64, xb, wp1, b1, h1);

  // 3) layer 2
  agg128_kernel<<<(NN + 3) / 4, 256, 0, stream>>>((const unsigned int*)h1, rs, col,
                                                  (unsigned int*)mean128, NN);
  mfma_gemm_kernel<128><<<NPAD / 128, 256, 0, stream>>>(mean128, h1, wp2, b2, h2);

  // 4) layer 3
  agg128_kernel<<<(NN + 3) / 4, 256, 0, stream>>>((const unsigned int*)h2, rs, col,
                                                  (unsigned int*)mean128, NN);
  mfma_gemm_kernel<128><<<NPAD / 128, 256, 0, stream>>>(mean128, h2, wp3, b3, h3);

  // 5) per-graph mean pool + tiny MLP (fp32)
  pool_kernel<<<NG * 8, 128, 0, stream>>>(h3, batch, pooled, NN);
  mlp_kernel<<<NG, 64, 0, stream>>>(pooled, batch, Wlin1, blin1, Wlin2, blin2, out, NN);
}

// Round 4
// 412.707 us; speedup vs baseline: 2.9081x; 1.1165x over previous
//
#include <hip/hip_runtime.h>
#include <hip/hip_bf16.h>
#include <cstdint>
#include <cstddef>

// Problem constants (match reference setup_inputs)
#define NN 100000     // nodes
#define NE 1600000    // edges
#define NG 64         // graphs
#define NPAD 100096   // NN padded to multiple of 128 (GEMM M-tile)
#define NBUK 782      // dst-buckets of 128 nodes: (NN+127)>>7
#define CAP 3072      // padded bucket capacity (expected 2046, sigma~45 -> 22 sigma)
#define NFB 256       // bucket_fill blocks
#define CHUNK 6250    // edges per fill block (NFB*CHUNK == NE)

typedef short short8v __attribute__((ext_vector_type(8)));
typedef float float4v __attribute__((ext_vector_type(4)));

// ---------------- helpers ----------------

__device__ __forceinline__ int lower_bound_i(const int* __restrict__ a, int n, int v) {
  int lo = 0, hi = n;
  while (lo < hi) { int m = (lo + hi) >> 1; if (a[m] < v) lo = m + 1; else hi = m; }
  return lo;
}

__device__ __forceinline__ float bf2f(ushort u) {
  return __uint_as_float(((unsigned int)u) << 16);
}

__device__ __forceinline__ float bflo(unsigned int u) {
  return __uint_as_float(u << 16);
}
__device__ __forceinline__ float bfhi(unsigned int u) {
  return __uint_as_float(u & 0xffff0000u);
}

__device__ __forceinline__ ushort f2bf(float f) {
  __hip_bfloat16 h = __float2bfloat16(f);   // RNE
  return *reinterpret_cast<ushort*>(&h);
}

// ---------------- dtype packing ----------------

// x fp32 [NN*64] -> bf16; also init bucket cursors (runs before bucket_fill)
__global__ void pack_x_kernel(const float* __restrict__ x, ushort* __restrict__ xb,
                              int* __restrict__ bcur) {
  int i4 = blockIdx.x * blockDim.x + threadIdx.x;
  if (i4 < NBUK) bcur[i4] = i4 * CAP;
  int idx = i4 * 4;
  if (idx >= NN * 64) return;
  float4 v = *(const float4*)(x + idx);
  ushort4 o;
  o.x = f2bf(v.x); o.y = f2bf(v.y); o.z = f2bf(v.z); o.w = f2bf(v.w);
  *(ushort4*)(xb + idx) = o;
}

// Pack [Wl;Wr] ([K x 128] each, fp32, row-major) into MFMA A-operand fragment order.
__device__ __forceinline__ void pack_one(const float* __restrict__ Wl,
                                         const float* __restrict__ Wr,
                                         ushort* __restrict__ Wp, int K, int idx) {
  int lane = idx & 63;
  int ft   = (idx >> 6) & 7;
  int kkp  = idx >> 9;
  int kbase = kkp * 32 + (lane >> 4) * 8;
  int isR = kbase >= K;
  const float* W = isR ? Wr : Wl;
  int k0 = kbase - (isR ? K : 0);
  int colf = ft * 16 + (lane & 15);
  ushort4 lo, hi;
  lo.x = f2bf(W[(k0 + 0) * 128 + colf]);
  lo.y = f2bf(W[(k0 + 1) * 128 + colf]);
  lo.z = f2bf(W[(k0 + 2) * 128 + colf]);
  lo.w = f2bf(W[(k0 + 3) * 128 + colf]);
  hi.x = f2bf(W[(k0 + 4) * 128 + colf]);
  hi.y = f2bf(W[(k0 + 5) * 128 + colf]);
  hi.z = f2bf(W[(k0 + 6) * 128 + colf]);
  hi.w = f2bf(W[(k0 + 7) * 128 + colf]);
  *(ushort4*)(Wp + (size_t)idx * 8)     = lo;
  *(ushort4*)(Wp + (size_t)idx * 8 + 4) = hi;
}

__global__ void pack_w_all_kernel(const float* __restrict__ Wl1, const float* __restrict__ Wr1,
                                  ushort* __restrict__ wp1,
                                  const float* __restrict__ Wl2, const float* __restrict__ Wr2,
                                  ushort* __restrict__ wp2,
                                  const float* __restrict__ Wl3, const float* __restrict__ Wr3,
                                  ushort* __restrict__ wp3) {
  int idx = blockIdx.x * blockDim.x + threadIdx.x;
  if (idx < 2048)       pack_one(Wl1, Wr1, wp1, 64,  idx);
  else if (idx < 6144)  pack_one(Wl2, Wr2, wp2, 128, idx - 2048);
  else if (idx < 10240) pack_one(Wl3, Wr3, wp3, 128, idx - 6144);
}

// ---------------- CSR build: two-level multisplit ----------------

// Phase 1: partition edges into padded dst-buckets. Per-block LDS histogram,
// one range-reservation atomic per (block,bucket), dense appended writes.
__global__ __launch_bounds__(256) void bucket_fill_kernel(const int* __restrict__ src,
                                                          const int* __restrict__ dst,
                                                          int* __restrict__ bcur,
                                                          unsigned int* __restrict__ bp) {
  __shared__ int lhist[NBUK];
  __shared__ int lbase[NBUK];
  int tid = threadIdx.x;
  int e0 = blockIdx.x * CHUNK;
  int e1 = e0 + CHUNK;   // NFB*CHUNK == NE exactly
  for (int i = tid; i < NBUK; i += 256) lhist[i] = 0;
  __syncthreads();
  for (int i = e0 + tid; i < e1; i += 256) atomicAdd(&lhist[dst[i] >> 7], 1);
  __syncthreads();
  for (int b = tid; b < NBUK; b += 256) {
    int c = lhist[b];
    lbase[b] = c ? atomicAdd(&bcur[b], c) : 0;
    lhist[b] = 0;   // reuse as local cursor
  }
  __syncthreads();
  for (int i = e0 + tid; i < e1; i += 256) {
    int d = dst[i];
    int b = d >> 7;
    int p = atomicAdd(&lhist[b], 1);
    int pos = lbase[b] + p;
    if (pos < (b + 1) * CAP)   // overflow guard (never triggers at CAP=3072)
      bp[pos] = ((unsigned int)(d & 127) << 17) | (unsigned int)src[i];
  }
}

// Phase 2: scan bucket counts -> boff (CSR bucket bases); also zero pooled, rs[NN].
__global__ __launch_bounds__(1024) void bucket_scan_kernel(const int* __restrict__ bcur,
                                                           int* __restrict__ boff,
                                                           int* __restrict__ rs,
                                                           float* __restrict__ pooled) {
  __shared__ int wsum[16];
  int tid = threadIdx.x, lane = tid & 63, wid = tid >> 6;
  int v = 0;
  if (tid < NBUK) v = min(bcur[tid] - tid * CAP, CAP);
  int incl = v;
  #pragma unroll
  for (int off = 1; off < 64; off <<= 1) {
    int t = __shfl_up(incl, off, 64);
    if (lane >= off) incl += t;
  }
  if (lane == 63) wsum[wid] = incl;
  __syncthreads();
  if (tid == 0) {
    int acc = 0;
    #pragma unroll
    for (int j = 0; j < 16; ++j) { int t = wsum[j]; wsum[j] = acc; acc += t; }
  }
  __syncthreads();
  int excl = incl - v + wsum[wid];
  if (tid <= NBUK) boff[tid] = excl;   // boff[NBUK] = NE (v==0 past end)
  for (int i = tid; i < NG * 128; i += 1024) pooled[i] = 0.f;
  if (tid == 0) rs[NN] = NE;
}

// Phase 3: one workgroup per bucket builds its CSR slice in LDS; col writes
// land in a contiguous L2-resident window.
__global__ __launch_bounds__(256) void bucket_csr_kernel(const unsigned int* __restrict__ bp,
                                                         const int* __restrict__ boff,
                                                         int* __restrict__ rs,
                                                         int* __restrict__ col) {
  __shared__ int sdeg[128], sinc[128], lcur[128];
  int b = blockIdx.x, tid = threadIdx.x;
  int n0 = b << 7;
  int e0 = boff[b], e1 = boff[b + 1];
  int cnt = e1 - e0;
  const unsigned int* __restrict__ mybp = bp + (size_t)b * CAP;
  if (tid < 128) sdeg[tid] = 0;
  __syncthreads();
  for (int i = tid; i < cnt; i += 256) atomicAdd(&sdeg[mybp[i] >> 17], 1);
  __syncthreads();
  if (tid < 128) sinc[tid] = sdeg[tid];
  __syncthreads();
  #pragma unroll
  for (int off = 1; off < 128; off <<= 1) {
    int add = 0;
    if (tid < 128 && tid >= off) add = sinc[tid - off];
    __syncthreads();
    if (tid < 128) sinc[tid] += add;
    __syncthreads();
  }
  if (tid < 128) {
    int excl = sinc[tid] - sdeg[tid];
    lcur[tid] = excl;
    int node = n0 + tid;
    if (node < NN) rs[node] = e0 + excl;
  }
  __syncthreads();
  for (int i = tid; i < cnt; i += 256) {
    unsigned int v = mybp[i];
    int p = atomicAdd(&lcur[v >> 17], 1);
    col[e0 + p] = (int)(v & 0x1FFFF);
  }
}

// ---------------- mean aggregation (gather over CSR, bf16, uint4 loads) ----------------
// d=64: rows are 32 uints (128B); 8 lanes x 16B per row -> 8 neighbors per load instr.

__global__ __launch_bounds__(256) void agg64_kernel(const unsigned int* __restrict__ X,
                                                    const int* __restrict__ rs,
                                                    const int* __restrict__ col,
                                                    unsigned int* __restrict__ out, int n) {
  int lane = threadIdx.x & 63;
  int node = blockIdx.x * 4 + (threadIdx.x >> 6);
  if (node >= n) return;
  int a = rs[node], b = rs[node + 1];
  int grp = lane >> 3, fl = lane & 7;
  float acc[8];
  #pragma unroll
  for (int j = 0; j < 8; ++j) acc[j] = 0.f;
  for (int jb = a; jb < b; jb += 64) {
    int v = (jb + lane < b) ? col[jb + lane] : 0;
    int cnt = min(64, b - jb);
    for (int t = 0; t < cnt; t += 8) {
      int idx = t + grp;
      int s = __shfl(v, min(idx, cnt - 1), 64);
      uint4 u = *(const uint4*)(X + (size_t)s * 32 + fl * 4);
      if (idx < cnt) {
        acc[0] += bflo(u.x); acc[1] += bfhi(u.x);
        acc[2] += bflo(u.y); acc[3] += bfhi(u.y);
        acc[4] += bflo(u.z); acc[5] += bfhi(u.z);
        acc[6] += bflo(u.w); acc[7] += bfhi(u.w);
      }
    }
  }
  #pragma unroll
  for (int off = 8; off <= 32; off <<= 1)
    #pragma unroll
    for (int j = 0; j < 8; ++j) acc[j] += __shfl_xor(acc[j], off, 64);
  int d = b - a;
  float inv = d > 0 ? 1.0f / (float)d : 0.f;
  if (grp == 0) {
    uint4 o;
    o.x = (unsigned int)f2bf(acc[0] * inv) | ((unsigned int)f2bf(acc[1] * inv) << 16);
    o.y = (unsigned int)f2bf(acc[2] * inv) | ((unsigned int)f2bf(acc[3] * inv) << 16);
    o.z = (unsigned int)f2bf(acc[4] * inv) | ((unsigned int)f2bf(acc[5] * inv) << 16);
    o.w = (unsigned int)f2bf(acc[6] * inv) | ((unsigned int)f2bf(acc[7] * inv) << 16);
    *(uint4*)(out + (size_t)node * 32 + fl * 4) = o;
  }
}

// d=128: rows are 64 uints (256B); 16 lanes x 16B per row -> 4 neighbors per load instr.
__global__ __launch_bounds__(256) void agg128_kernel(const unsigned int* __restrict__ X,
                                                     const int* __restrict__ rs,
                                                     const int* __restrict__ col,
                                                     unsigned int* __restrict__ out, int n) {
  int lane = threadIdx.x & 63;
  int node = blockIdx.x * 4 + (threadIdx.x >> 6);
  if (node >= n) return;
  int a = rs[node], b = rs[node + 1];
  int grp = lane >> 4, fl = lane & 15;
  float acc[8];
  #pragma unroll
  for (int j = 0; j < 8; ++j) acc[j] = 0.f;
  for (int jb = a; jb < b; jb += 64) {
    int v = (jb + lane < b) ? col[jb + lane] : 0;
    int cnt = min(64, b - jb);
    for (int t = 0; t < cnt; t += 4) {
      int idx = t + grp;
      int s = __shfl(v, min(idx, cnt - 1), 64);
      uint4 u = *(const uint4*)(X + (size_t)s * 64 + fl * 4);
      if (idx < cnt) {
        acc[0] += bflo(u.x); acc[1] += bfhi(u.x);
        acc[2] += bflo(u.y); acc[3] += bfhi(u.y);
        acc[4] += bflo(u.z); acc[5] += bfhi(u.z);
        acc[6] += bflo(u.w); acc[7] += bfhi(u.w);
      }
    }
  }
  #pragma unroll
  for (int off = 16; off <= 32; off <<= 1)
    #pragma unroll
    for (int j = 0; j < 8; ++j) acc[j] += __shfl_xor(acc[j], off, 64);
  int d = b - a;
  float inv = d > 0 ? 1.0f / (float)d : 0.f;
  if (grp == 0) {
    uint4 o;
    o.x = (unsigned int)f2bf(acc[0] * inv) | ((unsigned int)f2bf(acc[1] * inv) << 16);
    o.y = (unsigned int)f2bf(acc[2] * inv) | ((unsigned int)f2bf(acc[3] * inv) << 16);
    o.z = (unsigned int)f2bf(acc[4] * inv) | ((unsigned int)f2bf(acc[5] * inv) << 16);
    o.w = (unsigned int)f2bf(acc[6] * inv) | ((unsigned int)f2bf(acc[7] * inv) << 16);
    *(uint4*)(out + (size_t)node * 64 + fl * 4) = o;
  }
}

// ---------------- MFMA SAGE GEMM: Out = relu([Mean|X] @ [Wl;Wr] + b), bf16 ----------------

template <int K>
__global__ __launch_bounds__(256) void mfma_gemm_kernel(const ushort* __restrict__ Mean,
                                                        const ushort* __restrict__ Xb,
                                                        const ushort* __restrict__ Wp,
                                                        const float* __restrict__ bias,
                                                        ushort* __restrict__ Out) {
  constexpr int KS = K / 32;
  int lane = threadIdx.x & 63;
  int wave = threadIdx.x >> 6;
  int quad = lane >> 4;
  int l16  = lane & 15;
  size_t node0 = (size_t)blockIdx.x * 128 + wave * 32;

  float4v acc[2][8];
  #pragma unroll
  for (int g = 0; g < 2; ++g)
    #pragma unroll
    for (int ft = 0; ft < 8; ++ft)
      acc[g][ft] = (float4v){0.f, 0.f, 0.f, 0.f};

  #pragma unroll
  for (int s = 0; s < 2; ++s) {
    const ushort* __restrict__ A = s ? Xb : Mean;
    #pragma unroll
    for (int kk = 0; kk < KS; ++kk) {
      int kkp = s * KS + kk;
      short8v wv[8];
      const ushort* wb = Wp + ((size_t)(kkp * 8) * 64 + lane) * 8;
      #pragma unroll
      for (int ft = 0; ft < 8; ++ft)
        wv[ft] = *(const short8v*)(wb + (size_t)ft * 64 * 8);
      short8v av[2];
      #pragma unroll
      for (int g = 0; g < 2; ++g)
        av[g] = *(const short8v*)(A + (node0 + g * 16 + l16) * K + kk * 32 + quad * 8);
      #pragma unroll
      for (int g = 0; g < 2; ++g)
        #pragma unroll
        for (int ft = 0; ft < 8; ++ft)
          acc[g][ft] = __builtin_amdgcn_mfma_f32_16x16x32_bf16(wv[ft], av[g], acc[g][ft], 0, 0, 0);
    }
  }

  #pragma unroll
  for (int g = 0; g < 2; ++g) {
    size_t nrow = node0 + g * 16 + l16;
    #pragma unroll
    for (int ft = 0; ft < 8; ++ft) {
      float4 bb = *(const float4*)(bias + ft * 16 + quad * 4);
      float4v v = acc[g][ft];
      ushort4 o;
      o.x = f2bf(fmaxf(v.x + bb.x, 0.f));
      o.y = f2bf(fmaxf(v.y + bb.y, 0.f));
      o.z = f2bf(fmaxf(v.z + bb.z, 0.f));
      o.w = f2bf(fmaxf(v.w + bb.w, 0.f));
      *(ushort4*)(Out + nrow * 128 + ft * 16 + quad * 4) = o;
    }
  }
}

// ---------------- per-graph mean pool (batch sorted, bf16 input) ----------------
// 128 nodes per block; uint4 row loads; register accumulate with flush-on-graph-
// change into LDS partials; <=4 graphs per block (min graph ~1.3k nodes >> 128).

__global__ __launch_bounds__(256) void pool_kernel(const unsigned int* __restrict__ H,
                                                   const int* __restrict__ batch,
                                                   float* __restrict__ pooled) {
  __shared__ float part[4][128];
  int t = threadIdx.x;
  int fl = t & 15;     // uint4 index in row (features fl*8 .. fl*8+7)
  int sub = t >> 4;    // 0..15
  int n0 = blockIdx.x * 128;
  for (int i = t; i < 512; i += 256) ((float*)part)[i] = 0.f;
  int g0 = batch[n0];
  __syncthreads();
  float acc[8];
  #pragma unroll
  for (int j = 0; j < 8; ++j) acc[j] = 0.f;
  int curgi = 0;
  for (int i = 0; i < 8; ++i) {
    int node = n0 + sub + 16 * i;
    if (node >= NN) break;
    int gi = batch[node] - g0;
    if (gi != curgi) {
      if (curgi < 4) {
        #pragma unroll
        for (int j = 0; j < 8; ++j) {
          if (acc[j] != 0.f) atomicAdd(&part[curgi][fl * 8 + j], acc[j]);
          acc[j] = 0.f;
        }
      }
      curgi = gi;
    }
    uint4 u = *(const uint4*)(H + (size_t)node * 64 + fl * 4);
    if (curgi < 4) {
      acc[0] += bflo(u.x); acc[1] += bfhi(u.x);
      acc[2] += bflo(u.y); acc[3] += bfhi(u.y);
      acc[4] += bflo(u.z); acc[5] += bfhi(u.z);
      acc[6] += bflo(u.w); acc[7] += bfhi(u.w);
    } else {  // pathological fallback (never with ~1.3k-node min graphs)
      float* pg = &pooled[(g0 + gi) * 128 + fl * 8];
      atomicAdd(&pg[0], bflo(u.x)); atomicAdd(&pg[1], bfhi(u.x));
      atomicAdd(&pg[2], bflo(u.y)); atomicAdd(&pg[3], bfhi(u.y));
      atomicAdd(&pg[4], bflo(u.z)); atomicAdd(&pg[5], bfhi(u.z));
      atomicAdd(&pg[6], bflo(u.w)); atomicAdd(&pg[7], bfhi(u.w));
    }
  }
  if (curgi < 4) {
    #pragma unroll
    for (int j = 0; j < 8; ++j)
      if (acc[j] != 0.f) atomicAdd(&part[curgi][fl * 8 + j], acc[j]);
  }
  __syncthreads();
  int nlast = min(n0 + 127, NN - 1);
  int nslot = min(batch[nlast] - g0 + 1, 4);
  if (t < 128) {
    for (int s = 0; s < nslot; ++s) {
      float v = part[s][t];
      if (v != 0.f) atomicAdd(&pooled[(g0 + s) * 128 + t], v);
    }
  }
}

// ---------------- final MLP: relu(pooled/cnt @ W1 + b1) @ W2 + b2 (fp32) ----------------

__global__ __launch_bounds__(64) void mlp_kernel(const float* __restrict__ pooled,
                                                 const int* __restrict__ batch,
                                                 const float* __restrict__ W1,
                                                 const float* __restrict__ b1,
                                                 const float* __restrict__ W2,
                                                 const float* __restrict__ b2,
                                                 float* __restrict__ out, int n) {
  __shared__ float p[128];
  __shared__ float h1[64];
  int g = blockIdx.x, f = threadIdx.x;
  int lo = lower_bound_i(batch, n, g);
  int hi = lower_bound_i(batch, n, g + 1);
  float inv = (hi > lo) ? 1.0f / (float)(hi - lo) : 0.f;
  p[f]      = pooled[g * 128 + f] * inv;
  p[f + 64] = pooled[g * 128 + 64 + f] * inv;
  __syncthreads();
  float a = b1[f];
  #pragma unroll 8
  for (int k = 0; k < 128; ++k) a = fmaf(p[k], W1[k * 64 + f], a);
  a = fmaxf(a, 0.f);
  h1[f] = a;
  __syncthreads();
  float o = b2[f];
  #pragma unroll 8
  for (int k = 0; k < 64; ++k) o = fmaf(h1[k], W2[k * 64 + f], o);
  out[g * 64 + f] = o;
}

// ---------------- launch ----------------

extern "C" void kernel_launch(void* const* d_in, const int* in_sizes, int n_in,
                              void* d_out, int out_size, void* d_ws, size_t ws_size,
                              hipStream_t stream) {
  const float* x      = (const float*)d_in[0];
  const int*   edge   = (const int*)d_in[1];
  const int*   batch  = (const int*)d_in[2];
  const float* Wl1    = (const float*)d_in[3];
  const float* Wr1    = (const float*)d_in[4];
  const float* b1     = (const float*)d_in[5];
  const float* Wl2    = (const float*)d_in[6];
  const float* Wr2    = (const float*)d_in[7];
  const float* b2     = (const float*)d_in[8];
  const float* Wl3    = (const float*)d_in[9];
  const float* Wr3    = (const float*)d_in[10];
  const float* b3     = (const float*)d_in[11];
  const float* Wlin1  = (const float*)d_in[12];
  const float* blin1  = (const float*)d_in[13];
  const float* Wlin2  = (const float*)d_in[14];
  const float* blin2  = (const float*)d_in[15];
  float* out = (float*)d_out;

  const int* src = edge;        // edge_index[0]
  const int* dst = edge + NE;   // edge_index[1]

  // workspace carve-up (256B aligned)
  char* ws = (char*)d_ws;
  size_t off = 0;
  auto alloc = [&](size_t bytes) -> char* {
    char* p = ws + off;
    off = (off + bytes + 255) & ~(size_t)255;
    return p;
  };
  int*    rs     = (int*)alloc((size_t)(NN + 1) * 4);
  int*    col    = (int*)alloc((size_t)NE * 4);
  int*    bcur   = (int*)alloc((size_t)NBUK * 4);
  int*    boff   = (int*)alloc((size_t)(NBUK + 1) * 4);
  unsigned int* bp = (unsigned int*)alloc((size_t)NBUK * CAP * 4);
  ushort* xb     = (ushort*)alloc((size_t)NPAD * 64 * 2);
  ushort* mean64 = (ushort*)alloc((size_t)NPAD * 64 * 2);
  ushort* mean128= (ushort*)alloc((size_t)NPAD * 128 * 2);
  ushort* h1     = (ushort*)alloc((size_t)NPAD * 128 * 2);
  ushort* h2     = (ushort*)alloc((size_t)NPAD * 128 * 2);
  ushort* h3     = (ushort*)alloc((size_t)NPAD * 128 * 2);
  ushort* wp1    = (ushort*)alloc((size_t)2 * 64 * 128 * 2);
  ushort* wp2    = (ushort*)alloc((size_t)2 * 128 * 128 * 2);
  ushort* wp3    = (ushort*)alloc((size_t)2 * 128 * 128 * 2);
  float*  pooled = (float*)alloc((size_t)NG * 128 * 4);
  (void)ws_size; (void)n_in; (void)in_sizes; (void)out_size;

  // 1) packs + CSR build (multisplit)
  pack_x_kernel<<<(NN * 64 / 4 + 255) / 256, 256, 0, stream>>>(x, xb, bcur);
  pack_w_all_kernel<<<40, 256, 0, stream>>>(Wl1, Wr1, wp1, Wl2, Wr2, wp2, Wl3, Wr3, wp3);
  bucket_fill_kernel<<<NFB, 256, 0, stream>>>(src, dst, bcur, bp);
  bucket_scan_kernel<<<1, 1024, 0, stream>>>(bcur, boff, rs, pooled);
  bucket_csr_kernel<<<NBUK, 256, 0, stream>>>(bp, boff, rs, col);

  // 2) layer 1
  agg64_kernel<<<(NN + 3) / 4, 256, 0, stream>>>((const unsigned int*)xb, rs, col,
                                                 (unsigned int*)mean64, NN);
  mfma_gemm_kernel<64><<<NPAD / 128, 256, 0, stream>>>(mean64, xb, wp1, b1, h1);

  // 3) layer 2
  agg128_kernel<<<(NN + 3) / 4, 256, 0, stream>>>((const unsigned int*)h1, rs, col,
                                                  (unsigned int*)mean128, NN);
  mfma_gemm_kernel<128><<<NPAD / 128, 256, 0, stream>>>(mean128, h1, wp2, b2, h2);

  // 4) layer 3
  agg128_kernel<<<(NN + 3) / 4, 256, 0, stream>>>((const unsigned int*)h2, rs, col,
                                                  (unsigned int*)mean128, NN);
  mfma_gemm_kernel<128><<<NPAD / 128, 256, 0, stream>>>(mean128, h2, wp3, b3, h3);

  // 5) per-graph mean pool + tiny MLP (fp32)
  pool_kernel<<<(NN + 127) / 128, 256, 0, stream>>>((const unsigned int*)h3, batch, pooled);
  mlp_kernel<<<NG, 64, 0, stream>>>(pooled, batch, Wlin1, blin1, Wlin2, blin2, out, NN);
}